// Round 1
// baseline (298.685 us; speedup 1.0000x reference)
//
#include <hip/hip_runtime.h>
#include <hip/hip_bf16.h>

// weight_noise: out[i] = noise[i] * GAMMA * sqrt(sum_k (2^k * bit_k(w))^2) / 2^WF
// where w = trunc(x[i] * 2^WF), GAMMA=0.05, WF=14.
// sum_k 4^k * bit_k(w) == zero-interleave (spread) of w's bits to even positions.
// Purely elementwise, memory-bound: 12 B/element of HBM traffic.

__device__ __forceinline__ float sigma_of(float x) {
    // x in [0,1): trunc toward zero matches jnp astype(int32)
    unsigned w = (unsigned)(int)(x * 16384.0f);      // 14-bit value
    // spread bits: bit k -> bit 2k (handles up to 16 source bits)
    unsigned a = w;
    a = (a | (a << 8)) & 0x00FF00FFu;
    a = (a | (a << 4)) & 0x0F0F0F0Fu;
    a = (a | (a << 2)) & 0x33333333u;
    a = (a | (a << 1)) & 0x55555555u;
    // gamma * sqrt(acc) / 2^14  (power-of-two scale is exact)
    return (0.05f * sqrtf((float)a)) * (1.0f / 16384.0f);
}

__global__ __launch_bounds__(256) void weight_noise_kernel(
    const float4* __restrict__ x4,
    const float4* __restrict__ n4,
    float4* __restrict__ o4,
    int count4)
{
    int i = blockIdx.x * blockDim.x + threadIdx.x;
    if (i < count4) {
        float4 xv = x4[i];
        float4 nv = n4[i];
        float4 ov;
        ov.x = nv.x * sigma_of(xv.x);
        ov.y = nv.y * sigma_of(xv.y);
        ov.z = nv.z * sigma_of(xv.z);
        ov.w = nv.w * sigma_of(xv.w);
        o4[i] = ov;
    }
}

extern "C" void kernel_launch(void* const* d_in, const int* in_sizes, int n_in,
                              void* d_out, int out_size, void* d_ws, size_t ws_size,
                              hipStream_t stream) {
    const float4* x4 = (const float4*)d_in[0];       // x, float32
    const float4* nz = (const float4*)d_in[1];       // noise_n, float32
    float4* out = (float4*)d_out;                    // float32 output
    int n = in_sizes[0];                             // 4096*8192 = 33554432 (divisible by 4)
    int count4 = n / 4;
    int block = 256;
    int grid = (count4 + block - 1) / block;         // 32768 blocks
    weight_noise_kernel<<<grid, block, 0, stream>>>(x4, nz, out, count4);
}